// Round 8
// baseline (568.833 us; speedup 1.0000x reference)
//
#include <hip/hip_runtime.h>
#include <cstdint>
#include <cstddef>

#define BB 32
#define TT 300
#define DD 2312
#define HH 800
#define OO 10
#define CAP1 128
#define KMAX 32
#define HC 16                         // h-columns per c1 chunk
#define NCHUNK (HH / HC)              // 50

typedef float f32x4 __attribute__((ext_vector_type(4)));

// exp(-1/20), exp(-1/5) correctly rounded to fp32
#define DM_F 0.95122942450071400909f
#define DS_F 0.81873075307798185867f

// d_out float offsets (concatenated tuple, return order)
#define OUT_T_OFF 0
#define OUT_U_OFF 320
#define SUM_OFF   640
#define H1V_OFF   643ull
#define H2V_OFF   59187843ull
#define H1DV_OFF  59443843ull
#define H2DV_OFF  118631043ull
#define H1DT_OFF  118887043ull
#define H2DT_OFF  118912643ull

// ws byte offsets (all 256-aligned)
#define WS_C1     7398400ull
#define WS_IDX1   38118400ull        // u16[BB*TT*CAP1]
#define WS_CNT1   55936000ull        // int[BB*TT]
#define WS_T1     56012800ull        // int[BB*HH]
#define WS_DMP    56116480ull        // float[TT+1]
#define WS_DSP    56117760ull        // float[TT+1]
#define WS_TIMES1 56119040ull        // u16[BB*KMAX*DD] transposed (4,734,976 B)

// One wave per (b,din) row. Builds:
//  - per-(b,t) active-input lists (cnt1/idx1) for k_c1
//  - per-(b,d) ordered spike times, TRANSPOSED: times1T[(b*KMAX+j)*DD + d],
//    with a single 0xFFFF sentinel at position kbase (no memset needed)
// Block 0 threads 0/1 additionally build the dm/ds power tables.
__global__ void k_events(const float* __restrict__ in, int* __restrict__ cnt1,
                         unsigned short* __restrict__ idx1,
                         unsigned short* __restrict__ times1T,
                         float* __restrict__ dmp, float* __restrict__ dsp) {
    int row = blockIdx.x * 4 + (threadIdx.x >> 6);   // rows = BB*DD = 73984 (divisible by 4)
    int lane = threadIdx.x & 63;
    int b = row / DD, din = row - b * DD;
    const float* p = in + (size_t)row * TT;
    int kbase = 0;
    for (int r = 0; r < 5; ++r) {
        int t = r * 64 + lane;
        float v = (t < TT) ? p[t] : 0.f;
        bool act = (v != 0.f);
        unsigned long long m = __ballot(act);
        if (act) {
            int pos1 = atomicAdd(&cnt1[b * TT + t], 1);
            if (pos1 < CAP1) idx1[(size_t)(b * TT + t) * CAP1 + pos1] = (unsigned short)din;
            int pos = kbase + __popcll(m & ((1ull << lane) - 1ull));
            if (pos < KMAX)
                times1T[((size_t)b * KMAX + pos) * DD + din] = (unsigned short)t;
        }
        kbase += __popcll(m);
    }
    if (lane == 0 && kbase < KMAX)
        times1T[((size_t)b * KMAX + kbase) * DD + din] = 0xFFFFu;
    if (blockIdx.x == 0 && threadIdx.x < 2) {
        float base = (threadIdx.x == 0) ? DM_F : DS_F;
        float* tab = (threadIdx.x == 0) ? dmp : dsp;
        float v = 1.f;
        for (int i = 0; i <= TT; ++i) { tab[i] = v; v *= base; }
    }
}

// LDS-staged c1: block = (chunk, b); stages W1[h0:h0+16][:] (148 KB, contiguous,
// no transpose needed) into LDS, then thread t gathers its events from LDS.
// c1[b][t][h0..h0+15] written as 4x f32x4 (64B granule, coalesced-enough).
__global__ __launch_bounds__(320) void k_c1(const int* __restrict__ cnt1,
                                            const unsigned short* __restrict__ idx1,
                                            const float* __restrict__ W1,
                                            float* __restrict__ c1) {
    __shared__ float tile[HC * DD];   // 147,968 B
    int b = blockIdx.x & 31;
    int chunk = blockIdx.x >> 5;      // 0..49
    int h0 = chunk * HC;
    int tid = threadIdx.x;
    const f32x4* src = (const f32x4*)(W1 + (size_t)h0 * DD);
    f32x4* dst = (f32x4*)tile;
    for (int i = tid; i < HC * DD / 4; i += 320) dst[i] = src[i];
    __syncthreads();
    int t = tid;
    if (t >= TT) return;
    int blk = b * TT + t;
    int cnt = cnt1[blk];
    if (cnt > CAP1) cnt = CAP1;
    const unsigned short* lp = idx1 + (size_t)blk * CAP1;
    float acc[HC];
    #pragma unroll
    for (int c = 0; c < HC; ++c) acc[c] = 0.f;
    #pragma unroll 4
    for (int j = 0; j < cnt; ++j) {
        int din = lp[j];
        #pragma unroll
        for (int c = 0; c < HC; ++c) acc[c] += tile[c * DD + din];
    }
    float* op = c1 + (size_t)blk * HH + h0;
    #pragma unroll
    for (int q = 0; q < HC / 4; ++q) {
        f32x4 v = {acc[q * 4], acc[q * 4 + 1], acc[q * 4 + 2], acc[q * 4 + 3]};
        ((f32x4*)op)[q] = v;
    }
}

// Per-(b,h): branchless 300-step scan (latching selects, unconditional loads
// pipeline), first crossing -> t1, h1_dtdu.
__global__ void k_scan1(const float* __restrict__ c1, int* __restrict__ t1,
                        float* __restrict__ out) {
    int id = blockIdx.x * 64 + threadIdx.x;   // 25600 = 400 * 64
    int b = id / HH, h = id - b * HH;
    float um = 0.f, us = 0.f, umx = 0.f, usx = 0.f;
    int t1v = TT;
    const float* cbase = c1 + (size_t)b * TT * HH + h;
    #pragma unroll 4
    for (int t = 0; t < TT; ++t) {
        float c = cbase[(size_t)t * HH];
        um = um * DM_F + c;
        us = us * DS_F + c;
        bool cross = (um - us >= 1.0f) && (t1v == TT);
        t1v = cross ? t : t1v;
        umx = cross ? um : umx;
        usx = cross ? us : usx;
    }
    float dt = 0.f;
    if (t1v < TT) {
        float dudt = -umx / 20.0f + usx / 5.0f;
        dudt = (dudt >= 0.f) ? fmaxf(dudt, 1e-2f) : fminf(dudt, -1e-2f);
        dt = 1.f / dudt;
    }
    out[H1DT_OFF + (size_t)id] = dt;
    t1[id] = t1v;
}

// Layer-2 + h2 outputs, one block per b: build c2[o][t] in LDS from t1
// (parallel over h), 10 lanes scan -> out_t/out_u/h2_dtdu/t2(LDS), then all
// threads emit h2_v/h2_dvdt closed-form. Block 0 reduces sum_sp[0..1].
__global__ __launch_bounds__(256) void k_layer2(const int* __restrict__ t1,
                                                const int* __restrict__ cnt1,
                                                const float* __restrict__ W2,
                                                const float* __restrict__ dmp,
                                                const float* __restrict__ dsp,
                                                float* __restrict__ out) {
    __shared__ float c2[OO][TT];
    __shared__ int t1s[HH];
    __shared__ int t2s[OO];
    __shared__ int red[4];
    int b = blockIdx.x, tid = threadIdx.x;
    for (int i = tid; i < OO * TT; i += 256) ((float*)c2)[i] = 0.f;
    for (int h = tid; h < HH; h += 256) t1s[h] = t1[b * HH + h];
    __syncthreads();
    for (int h = tid; h < HH; h += 256) {
        int t = t1s[h];
        if (t < TT) {
            #pragma unroll
            for (int o = 0; o < OO; ++o) atomicAdd(&c2[o][t], W2[o * HH + h]);
        }
    }
    __syncthreads();
    bool done = false;
    if (tid < OO) {
        float um = 0.f, us = 0.f, u2 = 0.f, dtdu = 0.f;
        int t2v = TT;
        for (int t = 0; t < TT; ++t) {
            float c = c2[tid][t];
            um = um * DM_F + c;
            us = us * DS_F + c;
            float u = um - us;
            if (u >= 1.0f) {
                done = true; t2v = t; u2 = u;
                float dudt = -um / 20.0f + us / 5.0f;
                dudt = (dudt >= 0.f) ? fmaxf(dudt, 1e-2f) : fminf(dudt, -1e-2f);
                dtdu = 1.f / dudt;
                break;
            }
        }
        out[OUT_T_OFF + b * OO + tid] = (float)t2v;
        out[OUT_U_OFF + b * OO + tid] = done ? u2 : 0.f;
        out[H2DT_OFF + (size_t)(b * OO + tid)] = done ? dtdu : 0.f;
        t2s[tid] = t2v;
    }
    unsigned long long m = __ballot(done);
    if (tid == 0 && m) atomicAdd(&out[SUM_OFF + 2], (float)__popcll(m));
    __syncthreads();
    // h2_v / h2_dvdt closed form: vm2(t2)=dm^(t2-t1), vs2(t2)=ds^(t2-t1)
    for (int i = tid; i < OO * HH; i += 256) {
        int o = i / HH, h = i - o * HH;
        int t2v = t2s[o];
        float v = 0.f, dv = 0.f;
        if (t2v < TT) {
            int t1v = t1s[h];
            if (t1v <= t2v) {
                int k = t2v - t1v;
                float a = dmp[k], s = dsp[k];
                v = a - s;
                dv = a * 0.05f - s * 0.2f;
            }
        }
        size_t ro = (size_t)b * OO * HH + i;
        out[H2V_OFF + ro] = v;
        out[H2DV_OFF + ro] = dv;
    }

    if (blockIdx.x == 0) {
        int s0 = 0, s1 = 0;
        for (int i = tid; i < BB * TT; i += 256) s0 += cnt1[i];
        for (int i = tid; i < BB * HH; i += 256) s1 += (t1[i] < TT);
        for (int d = 32; d >= 1; d >>= 1) {
            s0 += __shfl_down(s0, d, 64);
            s1 += __shfl_down(s1, d, 64);
        }
        int w = tid >> 6;
        if ((tid & 63) == 0) red[w] = s0;
        __syncthreads();
        if (tid == 0) out[SUM_OFF + 0] = (float)(red[0] + red[1] + red[2] + red[3]);
        __syncthreads();
        if ((tid & 63) == 0) red[w] = s1;
        __syncthreads();
        if (tid == 0) out[SUM_OFF + 1] = (float)(red[0] + red[1] + red[2] + red[3]);
    }
}

// Event-based h1, one block per (b,h). Coalesced transposed time-list reads,
// aligned f32x4 nontemporal stores (out offsets are ==3 mod 4: 1 lead scalar,
// 577 float4 groups covering d=1..2308, 3 tail scalars).
struct AS { float a, s; };

__device__ __forceinline__ AS h1_accum(const unsigned short* __restrict__ tp,
                                       int d, int t1v,
                                       const float* __restrict__ sm,
                                       const float* __restrict__ ss) {
    AS r; r.a = 0.f; r.s = 0.f;
    #pragma unroll 1
    for (int j = 0; j < KMAX; ++j) {
        int ts = tp[(size_t)j * DD + d];
        if (ts > t1v) break;                 // ascending; sentinel 0xFFFF ends list
        int e = t1v - ts;
        r.a += sm[e]; r.s += ss[e];
    }
    return r;
}

__global__ __launch_bounds__(256) void k_h1ev(const int* __restrict__ t1,
                                              const unsigned short* __restrict__ times1T,
                                              const float* __restrict__ dmp,
                                              const float* __restrict__ dsp,
                                              float* __restrict__ out) {
    int blk = blockIdx.x;          // b*HH + h
    int b = blk / HH;
    int t1v = t1[blk];
    size_t rbase = (size_t)blk * DD;
    float* pv = out + H1V_OFF + rbase;
    float* pd = out + H1DV_OFF + rbase;
    int tid = threadIdx.x;
    if (t1v >= TT) {
        f32x4 z = {0.f, 0.f, 0.f, 0.f};
        for (int g = tid; g < 577; g += 256) {
            __builtin_nontemporal_store(z, (f32x4*)(pv + 1 + g * 4));
            __builtin_nontemporal_store(z, (f32x4*)(pd + 1 + g * 4));
        }
        if (tid < 4) {
            int d = (tid == 0) ? 0 : 2308 + tid;
            __builtin_nontemporal_store(0.f, pv + d);
            __builtin_nontemporal_store(0.f, pd + d);
        }
        return;
    }
    __shared__ float sm[TT], ss[TT];
    for (int i = tid; i < TT; i += 256) { sm[i] = dmp[i]; ss[i] = dsp[i]; }
    __syncthreads();
    const unsigned short* tp = times1T + (size_t)b * KMAX * DD;
    for (int g = tid; g < 577; g += 256) {
        int d0 = 1 + g * 4;
        AS r0 = h1_accum(tp, d0 + 0, t1v, sm, ss);
        AS r1 = h1_accum(tp, d0 + 1, t1v, sm, ss);
        AS r2 = h1_accum(tp, d0 + 2, t1v, sm, ss);
        AS r3 = h1_accum(tp, d0 + 3, t1v, sm, ss);
        f32x4 v4 = {r0.a - r0.s, r1.a - r1.s, r2.a - r2.s, r3.a - r3.s};
        f32x4 d4 = {r0.a * 0.05f - r0.s * 0.2f, r1.a * 0.05f - r1.s * 0.2f,
                    r2.a * 0.05f - r2.s * 0.2f, r3.a * 0.05f - r3.s * 0.2f};
        __builtin_nontemporal_store(v4, (f32x4*)(pv + d0));
        __builtin_nontemporal_store(d4, (f32x4*)(pd + d0));
    }
    if (tid < 4) {
        int d = (tid == 0) ? 0 : 2308 + tid;
        AS r = h1_accum(tp, d, t1v, sm, ss);
        __builtin_nontemporal_store(r.a - r.s, pv + d);
        __builtin_nontemporal_store(r.a * 0.05f - r.s * 0.2f, pd + d);
    }
}

extern "C" void kernel_launch(void* const* d_in, const int* in_sizes, int n_in,
                              void* d_out, int out_size, void* d_ws, size_t ws_size,
                              hipStream_t stream) {
    (void)in_sizes; (void)n_in; (void)out_size; (void)ws_size;
    const float* in = (const float*)d_in[0];
    const float* W1 = (const float*)d_in[1];
    const float* W2 = (const float*)d_in[2];
    float* out = (float*)d_out;
    char* ws = (char*)d_ws;

    float* c1  = (float*)(ws + WS_C1);
    unsigned short* idx1 = (unsigned short*)(ws + WS_IDX1);
    int* cnt1 = (int*)(ws + WS_CNT1);
    int* t1   = (int*)(ws + WS_T1);
    float* dmp = (float*)(ws + WS_DMP);
    float* dsp = (float*)(ws + WS_DSP);
    unsigned short* times1T = (unsigned short*)(ws + WS_TIMES1);

    (void)hipMemsetAsync(cnt1, 0, (size_t)BB * TT * 4, stream);
    (void)hipMemsetAsync(out + SUM_OFF, 0, 3 * sizeof(float), stream);

    k_events<<<(BB * DD) / 4, 256, 0, stream>>>(in, cnt1, idx1, times1T, dmp, dsp);
    k_c1<<<NCHUNK * BB, 320, 0, stream>>>(cnt1, idx1, W1, c1);
    k_scan1<<<(BB * HH) / 64, 64, 0, stream>>>(c1, t1, out);
    k_layer2<<<BB, 256, 0, stream>>>(t1, cnt1, W2, dmp, dsp, out);
    k_h1ev<<<BB * HH, 256, 0, stream>>>(t1, times1T, dmp, dsp, out);
}

// Round 9
// 426.049 us; speedup vs baseline: 1.3351x; 1.3351x over previous
//
#include <hip/hip_runtime.h>
#include <cstdint>
#include <cstddef>

#define BB 32
#define TT 300
#define DD 2312
#define HH 800
#define OO 10
#define CAP1 128
#define KMAX 32

typedef float f32x4 __attribute__((ext_vector_type(4)));

// exp(-1/20), exp(-1/5) correctly rounded to fp32
#define DM_F 0.95122942450071400909f
#define DS_F 0.81873075307798185867f

// d_out float offsets (concatenated tuple, return order)
#define OUT_T_OFF 0
#define OUT_U_OFF 320
#define SUM_OFF   640
#define H1V_OFF   643ull
#define H2V_OFF   59187843ull
#define H1DV_OFF  59443843ull
#define H2DV_OFF  118631043ull
#define H1DT_OFF  118887043ull
#define H2DT_OFF  118912643ull

// ws byte offsets (all 256-aligned)
#define WS_W1T    0ull
#define WS_C1     7398400ull
#define WS_IDX1   38118400ull        // u16[BB*TT*CAP1]
#define WS_CNT1   55936000ull        // int[BB*TT]
#define WS_T1     56012800ull        // int[BB*HH]
#define WS_DMP    56116480ull        // float[TT+1]
#define WS_DSP    56117760ull        // float[TT+1]
#define WS_TIMES1 56119040ull        // u16[BB*KMAX*DD] transposed (4,734,976 B)

__global__ void k_transpose(const float* __restrict__ W1, float* __restrict__ W1T) {
    __shared__ float tile[32][33];
    int dx = blockIdx.x * 32, hy = blockIdx.y * 32;
    int tx = threadIdx.x, ty = threadIdx.y;
    int d = dx + tx, h = hy + ty;            // h always < 800 (25*32)
    if (d < DD) tile[ty][tx] = W1[(size_t)h * DD + d];
    __syncthreads();
    int d2 = dx + ty, h2 = hy + tx;
    if (d2 < DD) W1T[(size_t)d2 * HH + h2] = tile[tx][ty];
}

// One wave per (b,din) row. Builds:
//  - per-(b,t) active-input lists (cnt1/idx1) for k_c1
//  - per-(b,d) ordered spike times, TRANSPOSED: times1T[(b*KMAX+j)*DD + d],
//    with a single 0xFFFF sentinel at position kbase (no memset needed)
// Block 0 threads 0/1 additionally build the dm/ds power tables.
__global__ void k_events(const float* __restrict__ in, int* __restrict__ cnt1,
                         unsigned short* __restrict__ idx1,
                         unsigned short* __restrict__ times1T,
                         float* __restrict__ dmp, float* __restrict__ dsp) {
    int row = blockIdx.x * 4 + (threadIdx.x >> 6);   // rows = BB*DD = 73984 (divisible by 4)
    int lane = threadIdx.x & 63;
    int b = row / DD, din = row - b * DD;
    const float* p = in + (size_t)row * TT;
    int kbase = 0;
    for (int r = 0; r < 5; ++r) {
        int t = r * 64 + lane;
        float v = (t < TT) ? p[t] : 0.f;
        bool act = (v != 0.f);
        unsigned long long m = __ballot(act);
        if (act) {
            int pos1 = atomicAdd(&cnt1[b * TT + t], 1);
            if (pos1 < CAP1) idx1[(size_t)(b * TT + t) * CAP1 + pos1] = (unsigned short)din;
            int pos = kbase + __popcll(m & ((1ull << lane) - 1ull));
            if (pos < KMAX)
                times1T[((size_t)b * KMAX + pos) * DD + din] = (unsigned short)t;
        }
        kbase += __popcll(m);
    }
    if (lane == 0 && kbase < KMAX)
        times1T[((size_t)b * KMAX + kbase) * DD + din] = 0xFFFFu;
    if (blockIdx.x == 0 && threadIdx.x < 2) {
        float base = (threadIdx.x == 0) ? DM_F : DS_F;
        float* tab = (threadIdx.x == 0) ? dmp : dsp;
        float v = 1.f;
        for (int i = 0; i <= TT; ++i) { tab[i] = v; v *= base; }
    }
}

// c1[b,t,chunk*400 : chunk*400+400] = sum over active din of W1T[din, chunk-half].
// Chunk-major grid: blocks [0,9600) touch only W1T columns 0:400 (3.7 MB,
// L2-resident per XCD), blocks [9600,19200) only columns 400:800.
__global__ __launch_bounds__(128) void k_c1(const int* __restrict__ cnt1,
                                            const unsigned short* __restrict__ idx1,
                                            const float* __restrict__ W1T,
                                            float* __restrict__ c1) {
    int blk = blockIdx.x % (BB * TT);     // b*TT + t
    int chunk = blockIdx.x / (BB * TT);   // 0 or 1
    int cnt = cnt1[blk];
    if (cnt > CAP1) cnt = CAP1;
    __shared__ int sidx[CAP1];
    for (int j = threadIdx.x; j < cnt; j += 128) sidx[j] = idx1[(size_t)blk * CAP1 + j];
    __syncthreads();
    int tid = threadIdx.x;
    if (tid < 100) {
        int v4i = chunk * 100 + tid;
        f32x4 acc = {0.f, 0.f, 0.f, 0.f};
        for (int j = 0; j < cnt; ++j) {
            const f32x4* row = (const f32x4*)(W1T + (size_t)sidx[j] * HH);
            acc += row[v4i];
        }
        ((f32x4*)(c1 + (size_t)blk * HH))[v4i] = acc;
    }
}

// Per-(b,h): branchless 300-step scan (latching selects, unconditional loads
// pipeline), first crossing -> t1, h1_dtdu.
__global__ void k_scan1(const float* __restrict__ c1, int* __restrict__ t1,
                        float* __restrict__ out) {
    int id = blockIdx.x * 64 + threadIdx.x;   // 25600 = 400 * 64
    int b = id / HH, h = id - b * HH;
    float um = 0.f, us = 0.f, umx = 0.f, usx = 0.f;
    int t1v = TT;
    const float* cbase = c1 + (size_t)b * TT * HH + h;
    #pragma unroll 4
    for (int t = 0; t < TT; ++t) {
        float c = cbase[(size_t)t * HH];
        um = um * DM_F + c;
        us = us * DS_F + c;
        bool cross = (um - us >= 1.0f) && (t1v == TT);
        t1v = cross ? t : t1v;
        umx = cross ? um : umx;
        usx = cross ? us : usx;
    }
    float dt = 0.f;
    if (t1v < TT) {
        float dudt = -umx / 20.0f + usx / 5.0f;
        dudt = (dudt >= 0.f) ? fmaxf(dudt, 1e-2f) : fminf(dudt, -1e-2f);
        dt = 1.f / dudt;
    }
    out[H1DT_OFF + (size_t)id] = dt;
    t1[id] = t1v;
}

// Layer-2 + h2 outputs, one block per b: build c2[o][t] in LDS from t1
// (parallel over h), 10 lanes scan -> out_t/out_u/h2_dtdu/t2(LDS), then all
// threads emit h2_v/h2_dvdt closed-form. Block 0 reduces sum_sp[0..1].
__global__ __launch_bounds__(256) void k_layer2(const int* __restrict__ t1,
                                                const int* __restrict__ cnt1,
                                                const float* __restrict__ W2,
                                                const float* __restrict__ dmp,
                                                const float* __restrict__ dsp,
                                                float* __restrict__ out) {
    __shared__ float c2[OO][TT];
    __shared__ int t1s[HH];
    __shared__ int t2s[OO];
    __shared__ int red[4];
    int b = blockIdx.x, tid = threadIdx.x;
    for (int i = tid; i < OO * TT; i += 256) ((float*)c2)[i] = 0.f;
    for (int h = tid; h < HH; h += 256) t1s[h] = t1[b * HH + h];
    __syncthreads();
    for (int h = tid; h < HH; h += 256) {
        int t = t1s[h];
        if (t < TT) {
            #pragma unroll
            for (int o = 0; o < OO; ++o) atomicAdd(&c2[o][t], W2[o * HH + h]);
        }
    }
    __syncthreads();
    bool done = false;
    if (tid < OO) {
        float um = 0.f, us = 0.f, u2 = 0.f, dtdu = 0.f;
        int t2v = TT;
        for (int t = 0; t < TT; ++t) {
            float c = c2[tid][t];
            um = um * DM_F + c;
            us = us * DS_F + c;
            float u = um - us;
            if (u >= 1.0f) {
                done = true; t2v = t; u2 = u;
                float dudt = -um / 20.0f + us / 5.0f;
                dudt = (dudt >= 0.f) ? fmaxf(dudt, 1e-2f) : fminf(dudt, -1e-2f);
                dtdu = 1.f / dudt;
                break;
            }
        }
        out[OUT_T_OFF + b * OO + tid] = (float)t2v;
        out[OUT_U_OFF + b * OO + tid] = done ? u2 : 0.f;
        out[H2DT_OFF + (size_t)(b * OO + tid)] = done ? dtdu : 0.f;
        t2s[tid] = t2v;
    }
    unsigned long long m = __ballot(done);
    if (tid == 0 && m) atomicAdd(&out[SUM_OFF + 2], (float)__popcll(m));
    __syncthreads();
    // h2_v / h2_dvdt closed form: vm2(t2)=dm^(t2-t1), vs2(t2)=ds^(t2-t1)
    for (int i = tid; i < OO * HH; i += 256) {
        int o = i / HH, h = i - o * HH;
        int t2v = t2s[o];
        float v = 0.f, dv = 0.f;
        if (t2v < TT) {
            int t1v = t1s[h];
            if (t1v <= t2v) {
                int k = t2v - t1v;
                float a = dmp[k], s = dsp[k];
                v = a - s;
                dv = a * 0.05f - s * 0.2f;
            }
        }
        size_t ro = (size_t)b * OO * HH + i;
        out[H2V_OFF + ro] = v;
        out[H2DV_OFF + ro] = dv;
    }

    if (blockIdx.x == 0) {
        int s0 = 0, s1 = 0;
        for (int i = tid; i < BB * TT; i += 256) s0 += cnt1[i];
        for (int i = tid; i < BB * HH; i += 256) s1 += (t1[i] < TT);
        for (int d = 32; d >= 1; d >>= 1) {
            s0 += __shfl_down(s0, d, 64);
            s1 += __shfl_down(s1, d, 64);
        }
        int w = tid >> 6;
        if ((tid & 63) == 0) red[w] = s0;
        __syncthreads();
        if (tid == 0) out[SUM_OFF + 0] = (float)(red[0] + red[1] + red[2] + red[3]);
        __syncthreads();
        if ((tid & 63) == 0) red[w] = s1;
        __syncthreads();
        if (tid == 0) out[SUM_OFF + 1] = (float)(red[0] + red[1] + red[2] + red[3]);
    }
}

// Event-based h1, one block per (b,h). Coalesced transposed time-list reads,
// aligned f32x4 nontemporal stores (out offsets are ==3 mod 4: 1 lead scalar,
// 577 float4 groups covering d=1..2308, 3 tail scalars).
struct AS { float a, s; };

__device__ __forceinline__ AS h1_accum(const unsigned short* __restrict__ tp,
                                       int d, int t1v,
                                       const float* __restrict__ sm,
                                       const float* __restrict__ ss) {
    AS r; r.a = 0.f; r.s = 0.f;
    #pragma unroll 1
    for (int j = 0; j < KMAX; ++j) {
        int ts = tp[(size_t)j * DD + d];
        if (ts > t1v) break;                 // ascending; sentinel 0xFFFF ends list
        int e = t1v - ts;
        r.a += sm[e]; r.s += ss[e];
    }
    return r;
}

__global__ __launch_bounds__(256) void k_h1ev(const int* __restrict__ t1,
                                              const unsigned short* __restrict__ times1T,
                                              const float* __restrict__ dmp,
                                              const float* __restrict__ dsp,
                                              float* __restrict__ out) {
    int blk = blockIdx.x;          // b*HH + h
    int b = blk / HH;
    int t1v = t1[blk];
    size_t rbase = (size_t)blk * DD;
    float* pv = out + H1V_OFF + rbase;
    float* pd = out + H1DV_OFF + rbase;
    int tid = threadIdx.x;
    if (t1v >= TT) {
        f32x4 z = {0.f, 0.f, 0.f, 0.f};
        for (int g = tid; g < 577; g += 256) {
            __builtin_nontemporal_store(z, (f32x4*)(pv + 1 + g * 4));
            __builtin_nontemporal_store(z, (f32x4*)(pd + 1 + g * 4));
        }
        if (tid < 4) {
            int d = (tid == 0) ? 0 : 2308 + tid;
            __builtin_nontemporal_store(0.f, pv + d);
            __builtin_nontemporal_store(0.f, pd + d);
        }
        return;
    }
    __shared__ float sm[TT], ss[TT];
    for (int i = tid; i < TT; i += 256) { sm[i] = dmp[i]; ss[i] = dsp[i]; }
    __syncthreads();
    const unsigned short* tp = times1T + (size_t)b * KMAX * DD;
    for (int g = tid; g < 577; g += 256) {
        int d0 = 1 + g * 4;
        AS r0 = h1_accum(tp, d0 + 0, t1v, sm, ss);
        AS r1 = h1_accum(tp, d0 + 1, t1v, sm, ss);
        AS r2 = h1_accum(tp, d0 + 2, t1v, sm, ss);
        AS r3 = h1_accum(tp, d0 + 3, t1v, sm, ss);
        f32x4 v4 = {r0.a - r0.s, r1.a - r1.s, r2.a - r2.s, r3.a - r3.s};
        f32x4 d4 = {r0.a * 0.05f - r0.s * 0.2f, r1.a * 0.05f - r1.s * 0.2f,
                    r2.a * 0.05f - r2.s * 0.2f, r3.a * 0.05f - r3.s * 0.2f};
        __builtin_nontemporal_store(v4, (f32x4*)(pv + d0));
        __builtin_nontemporal_store(d4, (f32x4*)(pd + d0));
    }
    if (tid < 4) {
        int d = (tid == 0) ? 0 : 2308 + tid;
        AS r = h1_accum(tp, d, t1v, sm, ss);
        __builtin_nontemporal_store(r.a - r.s, pv + d);
        __builtin_nontemporal_store(r.a * 0.05f - r.s * 0.2f, pd + d);
    }
}

extern "C" void kernel_launch(void* const* d_in, const int* in_sizes, int n_in,
                              void* d_out, int out_size, void* d_ws, size_t ws_size,
                              hipStream_t stream) {
    (void)in_sizes; (void)n_in; (void)out_size; (void)ws_size;
    const float* in = (const float*)d_in[0];
    const float* W1 = (const float*)d_in[1];
    const float* W2 = (const float*)d_in[2];
    float* out = (float*)d_out;
    char* ws = (char*)d_ws;

    float* W1T = (float*)(ws + WS_W1T);
    float* c1  = (float*)(ws + WS_C1);
    unsigned short* idx1 = (unsigned short*)(ws + WS_IDX1);
    int* cnt1 = (int*)(ws + WS_CNT1);
    int* t1   = (int*)(ws + WS_T1);
    float* dmp = (float*)(ws + WS_DMP);
    float* dsp = (float*)(ws + WS_DSP);
    unsigned short* times1T = (unsigned short*)(ws + WS_TIMES1);

    (void)hipMemsetAsync(cnt1, 0, (size_t)BB * TT * 4, stream);
    (void)hipMemsetAsync(out + SUM_OFF, 0, 3 * sizeof(float), stream);

    k_transpose<<<dim3(73, 25), dim3(32, 32), 0, stream>>>(W1, W1T);
    k_events<<<(BB * DD) / 4, 256, 0, stream>>>(in, cnt1, idx1, times1T, dmp, dsp);
    k_c1<<<2 * BB * TT, 128, 0, stream>>>(cnt1, idx1, W1T, c1);
    k_scan1<<<(BB * HH) / 64, 64, 0, stream>>>(c1, t1, out);
    k_layer2<<<BB, 256, 0, stream>>>(t1, cnt1, W2, dmp, dsp, out);
    k_h1ev<<<BB * HH, 256, 0, stream>>>(t1, times1T, dmp, dsp, out);
}